// Round 2
// baseline (456.497 us; speedup 1.0000x reference)
//
#include <hip/hip_runtime.h>
#include <hip/hip_cooperative_groups.h>
#include <math.h>

namespace cg = cooperative_groups;

// Problem constants (fixed by the reference's setup_inputs)
constexpr int N_  = 2;
constexpr int E_  = 16;
constexpr int C_  = 32;
constexpr int V_  = 48 * 160 * 160;   // 1,228,800 voxels per batch
constexpr int V4_ = V_ / 4;           // 307,200 float4 groups per batch
constexpr int BLK = 256;

// Cooperative geometry: 768 blocks = exactly 3 blocks/CU on 256 CUs.
constexpr int G_     = 768;
constexpr int HALF_  = G_ / 2;        // 384 blocks per batch
constexpr int WPB_   = HALF_ * 4;     // 1536 waves per batch
constexpr int VPW_   = V_ / WPB_;     // 800 voxels per wave
constexpr int NSTEP_ = VPW_ / 32;     // 25 K-steps of 32 voxels

constexpr float DELTA_VAR  = 0.5f;
constexpr float DELTA_DIST = 2.0f;
constexpr float GAMMA      = 0.001f;

// 8-way split accumulators (atomic decontention).
// ws floats: [0,8192) gsumT8[k][n][e][c] ; [8192,8704) gcnt8[k][n][c] ;
//            [8704,8720) gvar8[k][n]
constexpr int NCOPY     = 8;
constexpr int WS_SUMT   = 0;
constexpr int WS_CNT    = WS_SUMT + NCOPY * N_ * E_ * C_;   // 8192
constexpr int WS_VAR    = WS_CNT  + NCOPY * N_ * C_;        // 8704
constexpr int WS_FLOATS = WS_VAR  + NCOPY * N_;             // 8720

constexpr int MUP = 20;

using short8 = __attribute__((ext_vector_type(8))) short;
using f32x4  = __attribute__((ext_vector_type(4))) float;

__device__ __forceinline__ unsigned short f2bf(float f) {
    unsigned u = __float_as_uint(f);
    return (unsigned short)((u + 0x7FFFu + ((u >> 16) & 1u)) >> 16);
}
__device__ __forceinline__ unsigned packlab(int4 t) {
    return (unsigned)t.x | ((unsigned)t.y << 8) | ((unsigned)t.z << 16) | ((unsigned)t.w << 24);
}

// ---------------------------------------------------------------------------
// Phase 1: MFMA segmented sums + counts. NO LDS staging, NO barriers in the
// main loop: each lane loads its A-fragment slice (row e=myc, 8 consecutive
// voxels) directly from global and converts f32->bf16 in-register. Depth-2
// register prefetch. Epilogue: cross-wave LDS reduce + 8-way split atomics.
// ---------------------------------------------------------------------------
__device__ __forceinline__ void phase_sums(
    const float4* __restrict__ x4, const int4* __restrict__ t4,
    float* __restrict__ ws, float* s_red, int bid)
{
    const int tid  = threadIdx.x;
    const int lane = tid & 63;
    const int wid  = tid >> 6;
    const int myc  = lane & 15;
    const int quad = lane >> 4;

    const int n  = bid / HALF_;
    const int wb = (bid % HALF_) * 4 + wid;          // wave id within batch
    const float4* __restrict__ xrow = x4 + (size_t)(n * E_ + myc) * V4_;
    const int4*   __restrict__ t4n  = t4 + (size_t)n * V4_;
    const int l4 = wb * (VPW_ / 4) + quad * 2;       // float4 index of lane's first slice

    const short one = (short)0x3F80;
    short8 A_ones = {one, one, one, one, one, one, one, one};

    f32x4 acc_lo = {0.f,0.f,0.f,0.f}, acc_hi = {0.f,0.f,0.f,0.f};
    f32x4 cnt_lo = {0.f,0.f,0.f,0.f}, cnt_hi = {0.f,0.f,0.f,0.f};

    float4 RX0[3], RX1[3];
    int4   RP[3],  RQ[3];
    #pragma unroll
    for (int p = 0; p < 2; ++p) {
        RX0[p] = xrow[l4 + p * 8];
        RX1[p] = xrow[l4 + p * 8 + 1];
        RP[p]  = t4n[l4 + p * 8];
        RQ[p]  = t4n[l4 + p * 8 + 1];
    }

    #pragma unroll
    for (int s = 0; s < NSTEP_; ++s) {
        const int cur = s % 3;
        if (s + 2 < NSTEP_) {
            const int nxt = (s + 2) % 3;
            RX0[nxt] = xrow[l4 + (s + 2) * 8];
            RX1[nxt] = xrow[l4 + (s + 2) * 8 + 1];
            RP[nxt]  = t4n[l4 + (s + 2) * 8];
            RQ[nxt]  = t4n[l4 + (s + 2) * 8 + 1];
        }
        short8 A;
        A[0] = (short)f2bf(RX0[cur].x); A[1] = (short)f2bf(RX0[cur].y);
        A[2] = (short)f2bf(RX0[cur].z); A[3] = (short)f2bf(RX0[cur].w);
        A[4] = (short)f2bf(RX1[cur].x); A[5] = (short)f2bf(RX1[cur].y);
        A[6] = (short)f2bf(RX1[cur].z); A[7] = (short)f2bf(RX1[cur].w);

        const unsigned la  = packlab(RP[cur]);
        const unsigned lb2 = packlab(RQ[cur]);
        short8 Blo, Bhi;
        #pragma unroll
        for (int j = 0; j < 4; ++j) {
            const int c0 = (la  >> (8 * j)) & 255;
            const int c1 = (lb2 >> (8 * j)) & 255;
            Blo[j]     = (c0 == myc)      ? one : (short)0;
            Bhi[j]     = (c0 == myc + 16) ? one : (short)0;
            Blo[4 + j] = (c1 == myc)      ? one : (short)0;
            Bhi[4 + j] = (c1 == myc + 16) ? one : (short)0;
        }
        acc_lo = __builtin_amdgcn_mfma_f32_16x16x32_bf16(A,      Blo, acc_lo, 0, 0, 0);
        acc_hi = __builtin_amdgcn_mfma_f32_16x16x32_bf16(A,      Bhi, acc_hi, 0, 0, 0);
        cnt_lo = __builtin_amdgcn_mfma_f32_16x16x32_bf16(A_ones, Blo, cnt_lo, 0, 0, 0);
        cnt_hi = __builtin_amdgcn_mfma_f32_16x16x32_bf16(A_ones, Bhi, cnt_hi, 0, 0, 0);
    }

    // cross-wave LDS reduce: 2048 sums + 128 counts
    #pragma unroll
    for (int r = 0; r < 4; ++r) {
        s_red[wid * 512 + lane * 8 + r]     = acc_lo[r];
        s_red[wid * 512 + lane * 8 + 4 + r] = acc_hi[r];
    }
    if (quad == 0) {
        s_red[2048 + wid * 32 + myc]      = cnt_lo[0];
        s_red[2048 + wid * 32 + myc + 16] = cnt_hi[0];
    }
    __syncthreads();

    const int kc = bid & (NCOPY - 1);
    float* gsumT = ws + WS_SUMT + kc * (N_ * E_ * C_);
    float* gcntk = ws + WS_CNT  + kc * (N_ * C_);
    #pragma unroll
    for (int u = 0; u < 2; ++u) {
        const int combo = tid * 2 + u;              // 0..511
        const int l = combo >> 3, k = combo & 7;
        const int e = (l >> 4) * 4 + (k & 3);
        const int c = (l & 15) + 16 * (k >> 2);
        const float v = s_red[combo] + s_red[512 + combo]
                      + s_red[1024 + combo] + s_red[1536 + combo];
        unsafeAtomicAdd(&gsumT[(n * E_ + e) * C_ + c], v);
    }
    if (tid < C_) {
        const float v = s_red[2048 + tid] + s_red[2048 + 32 + tid]
                      + s_red[2048 + 64 + tid] + s_red[2048 + 96 + tid];
        unsafeAtomicAdd(&gcntk[n * C_ + tid], v);
    }
}

// ---------------------------------------------------------------------------
// Phase 2: variance. mu tables for BOTH batches in LDS; grid-stride over all
// v4 groups; x read f32 (LLC-warm). Block reduce -> 8-way split gvar atomics.
// s_mu must have >= N_*C_*MUP + 16 floats (tail = wave partial scratch).
// ---------------------------------------------------------------------------
__device__ __forceinline__ void phase_var(
    const float4* __restrict__ x4, const int4* __restrict__ t4,
    float* __restrict__ ws, float* s_mu, int bid, int nblk)
{
    const float* gsumT = ws + WS_SUMT;
    const float* gcnt  = ws + WS_CNT;
    float*       gvar  = ws + WS_VAR;
    const int tid = threadIdx.x;

    for (int i = tid; i < N_ * C_ * E_; i += BLK) {
        const int n2 = i >> 9;            // C_*E_ = 512
        const int r  = i & 511;
        const int c  = r >> 4, e = r & 15;
        float s = 0.f, cc = 0.f;
        #pragma unroll
        for (int k = 0; k < NCOPY; ++k) {
            s  += gsumT[k * (N_ * E_ * C_) + (n2 * E_ + e) * C_ + c];
            cc += gcnt [k * (N_ * C_) + n2 * C_ + c];
        }
        s_mu[n2 * (C_ * MUP) + c * MUP + e] = s / cc;
        if (e == 0) s_mu[n2 * (C_ * MUP) + c * MUP + 16] = 1.0f / (cc * (float)C_);
    }
    __syncthreads();

    float va0 = 0.f, va1 = 0.f;
    for (int g = bid * BLK + tid; g < N_ * V4_; g += nblk * BLK) {
        const int n  = (g >= V4_) ? 1 : 0;
        const int vg = g - n * V4_;
        const int4 t = t4[g];
        const float4* __restrict__ xr = x4 + (size_t)n * E_ * V4_ + vg;
        float4 xs[16];
        #pragma unroll
        for (int e = 0; e < 16; ++e) xs[e] = xr[(size_t)e * V4_];

        const float* mu = s_mu + n * (C_ * MUP);
        const int l0 = t.x, l1 = t.y, l2 = t.z, l3 = t.w;
        float4 m0[4], m1[4], m2[4], m3[4];
        #pragma unroll
        for (int u = 0; u < 4; ++u) {
            m0[u] = *(const float4*)&mu[l0 * MUP + 4 * u];
            m1[u] = *(const float4*)&mu[l1 * MUP + 4 * u];
            m2[u] = *(const float4*)&mu[l2 * MUP + 4 * u];
            m3[u] = *(const float4*)&mu[l3 * MUP + 4 * u];
        }
        const float w0 = mu[l0 * MUP + 16], w1 = mu[l1 * MUP + 16];
        const float w2 = mu[l2 * MUP + 16], w3 = mu[l3 * MUP + 16];

        float d0 = 0.f, d1 = 0.f, d2 = 0.f, d3 = 0.f;
        #pragma unroll
        for (int e = 0; e < 16; ++e) {
            const float mu0 = ((const float*)&m0[e >> 2])[e & 3];
            const float mu1 = ((const float*)&m1[e >> 2])[e & 3];
            const float mu2 = ((const float*)&m2[e >> 2])[e & 3];
            const float mu3 = ((const float*)&m3[e >> 2])[e & 3];
            d0 += (xs[e].x - mu0) * (xs[e].x - mu0);
            d1 += (xs[e].y - mu1) * (xs[e].y - mu1);
            d2 += (xs[e].z - mu2) * (xs[e].z - mu2);
            d3 += (xs[e].w - mu3) * (xs[e].w - mu3);
        }
        const float h0 = fmaxf(sqrtf(d0) - DELTA_VAR, 0.f);
        const float h1 = fmaxf(sqrtf(d1) - DELTA_VAR, 0.f);
        const float h2 = fmaxf(sqrtf(d2) - DELTA_VAR, 0.f);
        const float h3 = fmaxf(sqrtf(d3) - DELTA_VAR, 0.f);
        const float vv = h0 * h0 * w0 + h1 * h1 * w1 + h2 * h2 * w2 + h3 * h3 * w3;
        va0 += (n == 0) ? vv : 0.f;
        va1 += (n == 0) ? 0.f : vv;
    }

    #pragma unroll
    for (int off = 32; off > 0; off >>= 1) {
        va0 += __shfl_down(va0, off, 64);
        va1 += __shfl_down(va1, off, 64);
    }
    const int base = N_ * C_ * MUP;   // 1280
    if ((tid & 63) == 0) {
        s_mu[base + (tid >> 6) * 2]     = va0;
        s_mu[base + (tid >> 6) * 2 + 1] = va1;
    }
    __syncthreads();
    if (tid == 0) {
        const float t0 = s_mu[base] + s_mu[base + 2] + s_mu[base + 4] + s_mu[base + 6];
        const float t1 = s_mu[base + 1] + s_mu[base + 3] + s_mu[base + 5] + s_mu[base + 7];
        const int kc = bid & (NCOPY - 1);
        unsafeAtomicAdd(&gvar[kc * N_ + 0], t0);
        unsafeAtomicAdd(&gvar[kc * N_ + 1], t1);
    }
}

// ---------------------------------------------------------------------------
// Phase 3 (single block): repulsion + regularizer + assemble. sm >= 640 floats.
// ---------------------------------------------------------------------------
__device__ __forceinline__ void phase_fin(
    const float* __restrict__ ws, float* __restrict__ out, float* sm)
{
    const float* gsumT = ws + WS_SUMT;
    const float* gcnt  = ws + WS_CNT;
    const float* gvar  = ws + WS_VAR;

    if (threadIdx.x == 0) sm[601] = 0.0f;

    for (int n = 0; n < N_; ++n) {
        __syncthreads();
        for (int i = threadIdx.x; i < C_ * E_; i += BLK) {
            const int c = i >> 4, e = i & 15;
            float s = 0.f, cc = 0.f;
            #pragma unroll
            for (int k = 0; k < NCOPY; ++k) {
                s  += gsumT[k * (N_ * E_ * C_) + (n * E_ + e) * C_ + c];
                cc += gcnt [k * (N_ * C_) + n * C_ + c];
            }
            sm[c * 17 + e] = s / cc;
        }
        if (threadIdx.x == 0) {
            float vs = 0.f;
            #pragma unroll
            for (int k = 0; k < NCOPY; ++k) vs += gvar[k * N_ + n];
            sm[600] = vs;
        }
        __syncthreads();

        float local = 0.0f;
        if (threadIdx.x < C_) {
            const int c = threadIdx.x;
            float d2 = 0.f;
            #pragma unroll
            for (int e = 0; e < E_; ++e) {
                const float m = sm[c * 17 + e];
                d2 += m * m;
            }
            const float nm = d2 > 0.f ? sqrtf(d2) : 0.f;
            local += GAMMA * nm / (float)C_;
        }
        for (int t = threadIdx.x; t < C_ * C_; t += BLK) {
            const int i = t >> 5, j = t & 31;
            if (i != j) {
                float d2 = 0.f;
                #pragma unroll
                for (int e = 0; e < E_; ++e) {
                    const float diff = sm[i * 17 + e] - sm[j * 17 + e];
                    d2 += diff * diff;
                }
                const float d = d2 > 0.f ? sqrtf(d2) : 0.f;
                const float h = fmaxf(2.0f * DELTA_DIST - d, 0.f);
                local += (h * h) / (float)(C_ * (C_ - 1));
            }
        }
        unsafeAtomicAdd(&sm[600], local);
        __syncthreads();
        if (threadIdx.x == 0) sm[601] += sm[600];
    }
    __syncthreads();
    if (threadIdx.x == 0) out[0] = sm[601] / (float)N_;
}

// ---------------------------------------------------------------------------
// Fused cooperative kernel + standalone fallbacks
// ---------------------------------------------------------------------------
__global__ __launch_bounds__(BLK, 3) void fused_all(
    const float4* __restrict__ x4, const int4* __restrict__ t4,
    float* __restrict__ ws, float* __restrict__ out)
{
    __shared__ float s_red[2176];                 // 8704 B: sums epilogue
    __shared__ float s_mu[N_ * C_ * MUP + 16];    // 5184 B: mu tables + partials
    const int bid = blockIdx.x;

    phase_sums(x4, t4, ws, s_red, bid);
    cg::this_grid().sync();
    phase_var(x4, t4, ws, s_mu, bid, (int)gridDim.x);
    cg::this_grid().sync();
    if (bid == 0) phase_fin(ws, out, s_mu);
}

__global__ __launch_bounds__(BLK, 3) void k_sums(
    const float4* __restrict__ x4, const int4* __restrict__ t4,
    float* __restrict__ ws)
{
    __shared__ float s_red[2176];
    phase_sums(x4, t4, ws, s_red, blockIdx.x);
}

__global__ __launch_bounds__(BLK, 3) void k_var(
    const float4* __restrict__ x4, const int4* __restrict__ t4,
    float* __restrict__ ws)
{
    __shared__ float s_mu[N_ * C_ * MUP + 16];
    phase_var(x4, t4, ws, s_mu, blockIdx.x, (int)gridDim.x);
}

__global__ __launch_bounds__(BLK) void k_fin(
    const float* __restrict__ ws, float* __restrict__ out)
{
    __shared__ float sm[N_ * C_ * MUP + 16];
    phase_fin(ws, out, sm);
}

// ---------------------------------------------------------------------------
extern "C" void kernel_launch(void* const* d_in, const int* in_sizes, int n_in,
                              void* d_out, int out_size, void* d_ws, size_t ws_size,
                              hipStream_t stream) {
    const float4* x4 = (const float4*)d_in[0];
    const int4*   t4 = (const int4*)d_in[1];
    float* ws  = (float*)d_ws;
    float* out = (float*)d_out;

    hipMemsetAsync(d_ws, 0, WS_FLOATS * sizeof(float), stream);

    void* args[] = {(void*)&x4, (void*)&t4, (void*)&ws, (void*)&out};
    hipError_t err = hipLaunchCooperativeKernel(
        (const void*)fused_all, dim3(G_), dim3(BLK), args, 0, stream);
    if (err != hipSuccess) {
        (void)hipGetLastError();   // clear error state, take the 3-launch path
        k_sums<<<dim3(G_), BLK, 0, stream>>>(x4, t4, ws);
        k_var <<<dim3(G_), BLK, 0, stream>>>(x4, t4, ws);
        k_fin <<<1,        BLK, 0, stream>>>(ws, out);
    }
}

// Round 3
// 443.723 us; speedup vs baseline: 1.0288x; 1.0288x over previous
//
#include <hip/hip_runtime.h>
#include <math.h>

// Problem constants (fixed by the reference's setup_inputs)
constexpr int N_  = 2;
constexpr int E_  = 16;
constexpr int C_  = 32;
constexpr int V_  = 48 * 160 * 160;   // 1,228,800 voxels per batch
constexpr int V4_ = V_ / 4;           // 307,200 float4 groups per batch
constexpr int BLK = 256;

constexpr int TILE = 512;
constexpr int TPN_ = V_ / TILE;       // 2400 tiles per batch
constexpr int GS   = 1024;            // sums grid: exactly 4 blocks/CU resident
constexpr int SPB_ = GS / N_;         // 512 sums-blocks per batch
constexpr int GV   = 1024;            // variance grid

constexpr float DELTA_VAR  = 0.5f;
constexpr float DELTA_DIST = 2.0f;
constexpr float GAMMA      = 0.001f;

// ws layout (floats):
//   [0,8192)      gsumT8 [k][n][e][c]
//   [8192,8704)   gcnt8  [k][n][c]
//   [8704,8720)   gvar8  [k][n]
//   [8720]        ticket1 (sums)   [8721] ticket2 (var)
//   [8728,10008)  mu     [n][c][MUP]  (16 means + w at slot 16)
constexpr int NCOPY     = 8;
constexpr int MUP       = 20;
constexpr int WS_SUMT   = 0;
constexpr int WS_CNT    = WS_SUMT + NCOPY * N_ * E_ * C_;   // 8192
constexpr int WS_VAR    = WS_CNT  + NCOPY * N_ * C_;        // 8704
constexpr int WS_TK1    = WS_VAR  + NCOPY * N_;             // 8720
constexpr int WS_TK2    = WS_TK1 + 1;                       // 8721
constexpr int WS_MU     = 8728;
constexpr int WS_FLOATS = WS_MU + N_ * C_ * MUP;            // 10008

using short8 = __attribute__((ext_vector_type(8))) short;
using f32x4  = __attribute__((ext_vector_type(4))) float;

__device__ __forceinline__ unsigned short f2bf(float f) {
    unsigned u = __float_as_uint(f);
    return (unsigned short)((u + 0x7FFFu + ((u >> 16) & 1u)) >> 16);
}
__device__ __forceinline__ unsigned packlab(int4 t) {
    return (unsigned)t.x | ((unsigned)t.y << 8) | ((unsigned)t.z << 16) | ((unsigned)t.w << 24);
}
// agent-scope (device-coherent) load: reads the LLC-fresh value written by
// other blocks' device-scope atomics, bypassing possibly-stale L1/L2.
__device__ __forceinline__ float gload(const float* p) {
    return __hip_atomic_load(p, __ATOMIC_RELAXED, __HIP_MEMORY_SCOPE_AGENT);
}

// ---------------------------------------------------------------------------
// Kernel 1: MFMA segmented sums + counts. Persistent blocks: block b owns
// batch n=b&1 and tiles (b>>1) + i*512 (4 or 5 tiles). Per tile: staged
// bf16 LDS (double-buffered), register prefetch of the next tile, lgkm-only
// barrier (global loads stay in flight). Epilogue: cross-wave LDS reduce +
// 8-way split atomics. LAST block (ticket) computes the mu table into ws.
// ---------------------------------------------------------------------------
constexpr int XPAD = 520;   // bf16 row stride for the 512-voxel tile
__global__ __launch_bounds__(BLK, 4) void k_sums(
    const float4* __restrict__ x4, const int4* __restrict__ t4,
    float* __restrict__ ws)
{
    __shared__ unsigned short s_xb[2][E_ * XPAD];   // 33,280 B -> 4 blocks/CU
    __shared__ unsigned s_flag;

    const int b    = blockIdx.x;
    const int tid  = threadIdx.x;
    const int lane = tid & 63;
    const int wid  = tid >> 6;
    const int myc  = lane & 15;
    const int quad = lane >> 4;

    const int n  = b & 1;
    const int bs = b >> 1;                       // first tile within batch
    const int nt = (bs < (TPN_ - 4 * SPB_)) ? 5 : 4;   // 2400 = 4*512 + 352

    const float4* __restrict__ xn  = x4 + (size_t)(n * E_) * V4_;
    const int4*   __restrict__ t4n = t4 + (size_t)n * V4_;

    const short one = (short)0x3F80;
    short8 A_ones = {one, one, one, one, one, one, one, one};

    f32x4 acc_lo = {0.f,0.f,0.f,0.f}, acc_hi = {0.f,0.f,0.f,0.f};
    f32x4 cnt_lo = {0.f,0.f,0.f,0.f}, cnt_hi = {0.f,0.f,0.f,0.f};

    // prologue: tile 0 loads
    float4 R[8];
    {
        const int tb4 = bs * (TILE / 4);
        #pragma unroll
        for (int k = 0; k < 8; ++k) {
            const int i = k * BLK + tid, e = i >> 7, v4 = i & 127;
            R[k] = xn[(size_t)e * V4_ + tb4 + v4];
        }
    }

    for (int it = 0; it < nt; ++it) {
        const int tbase4 = (bs + it * SPB_) * (TILE / 4);
        unsigned short* buf = s_xb[it & 1];

        // convert + LDS stage
        #pragma unroll
        for (int k = 0; k < 8; ++k) {
            const int i = k * BLK + tid, e = i >> 7, v4 = i & 127;
            uint2 p;
            p.x = (unsigned)f2bf(R[k].x) | ((unsigned)f2bf(R[k].y) << 16);
            p.y = (unsigned)f2bf(R[k].z) | ((unsigned)f2bf(R[k].w) << 16);
            *(uint2*)&buf[e * XPAD + v4 * 4] = p;
        }
        // prefetch next tile — stays in flight across the raw barrier
        if (it + 1 < nt) {
            const int nb4 = (bs + (it + 1) * SPB_) * (TILE / 4);
            #pragma unroll
            for (int k = 0; k < 8; ++k) {
                const int i = k * BLK + tid, e = i >> 7, v4 = i & 127;
                R[k] = xn[(size_t)e * V4_ + nb4 + v4];
            }
        }
        // labels for this tile — also in flight across the barrier
        const int wbase = wid * 128;
        int4 P[4], Q[4];
        #pragma unroll
        for (int s = 0; s < 4; ++s) {
            const int b4 = tbase4 + ((wbase + s * 32 + quad * 8) >> 2);
            P[s] = t4n[b4];
            Q[s] = t4n[b4 + 1];
        }

        // lgkm-only barrier: orders ds_writes without draining vmcnt
        __builtin_amdgcn_sched_barrier(0);
        asm volatile("s_waitcnt lgkmcnt(0)");
        __builtin_amdgcn_s_barrier();
        __builtin_amdgcn_sched_barrier(0);

        // MFMA phase: 4 K-steps of 32 voxels over this wave's 128-voxel strip
        #pragma unroll
        for (int s = 0; s < 4; ++s) {
            const int lvb = wbase + s * 32;
            const short8 A = *(const short8*)&buf[myc * XPAD + lvb + quad * 8];
            const unsigned la = packlab(P[s]), lb2 = packlab(Q[s]);
            short8 Blo, Bhi;
            #pragma unroll
            for (int j = 0; j < 4; ++j) {
                const int c0 = (la  >> (8 * j)) & 255;
                const int c1 = (lb2 >> (8 * j)) & 255;
                Blo[j]     = (c0 == myc)      ? one : (short)0;
                Bhi[j]     = (c0 == myc + 16) ? one : (short)0;
                Blo[4 + j] = (c1 == myc)      ? one : (short)0;
                Bhi[4 + j] = (c1 == myc + 16) ? one : (short)0;
            }
            acc_lo = __builtin_amdgcn_mfma_f32_16x16x32_bf16(A,      Blo, acc_lo, 0, 0, 0);
            acc_hi = __builtin_amdgcn_mfma_f32_16x16x32_bf16(A,      Bhi, acc_hi, 0, 0, 0);
            cnt_lo = __builtin_amdgcn_mfma_f32_16x16x32_bf16(A_ones, Blo, cnt_lo, 0, 0, 0);
            cnt_hi = __builtin_amdgcn_mfma_f32_16x16x32_bf16(A_ones, Bhi, cnt_hi, 0, 0, 0);
        }
    }

    // ---- epilogue: cross-wave LDS reduce (overlay buffer 0 — barrier first
    // since the last tile may have used buffer 0 when nt is odd)
    __syncthreads();
    float* s_red = (float*)&s_xb[0][0];   // 2048 sums + 128 counts
    #pragma unroll
    for (int r = 0; r < 4; ++r) {
        s_red[wid * 512 + lane * 8 + r]     = acc_lo[r];
        s_red[wid * 512 + lane * 8 + 4 + r] = acc_hi[r];
    }
    if (quad == 0) {
        s_red[2048 + wid * 32 + myc]      = cnt_lo[0];
        s_red[2048 + wid * 32 + myc + 16] = cnt_hi[0];
    }
    __syncthreads();

    const int kc = bs & (NCOPY - 1);
    float* gsumT = ws + WS_SUMT + kc * (N_ * E_ * C_);
    float* gcntk = ws + WS_CNT  + kc * (N_ * C_);
    #pragma unroll
    for (int u = 0; u < 2; ++u) {
        const int combo = tid * 2 + u;              // 0..511
        const int l = combo >> 3, k = combo & 7;
        const int e = (l >> 4) * 4 + (k & 3);
        const int c = (l & 15) + 16 * (k >> 2);
        const float v = s_red[combo] + s_red[512 + combo]
                      + s_red[1024 + combo] + s_red[1536 + combo];
        unsafeAtomicAdd(&gsumT[(n * E_ + e) * C_ + c], v);
    }
    if (tid < C_) {
        const float v = s_red[2048 + tid] + s_red[2048 + 32 + tid]
                      + s_red[2048 + 64 + tid] + s_red[2048 + 96 + tid];
        unsafeAtomicAdd(&gcntk[n * C_ + tid], v);
    }

    // ---- ticket: last block builds the mu table (means + hinge weights)
    __threadfence();                 // my atomics globally visible
    __syncthreads();                 // all threads' atomics fenced
    if (tid == 0) {
        unsigned* tk = (unsigned*)(ws + WS_TK1);
        s_flag = (atomicAdd(tk, 1u) == (unsigned)(GS - 1)) ? 1u : 0u;
    }
    __syncthreads();
    if (s_flag) {
        __threadfence();             // acquire
        const float* gS = ws + WS_SUMT;
        const float* gC = ws + WS_CNT;
        float*       mu = ws + WS_MU;
        for (int i = tid; i < N_ * C_ * E_; i += BLK) {
            const int n2 = i >> 9;            // C_*E_ = 512
            const int r  = i & 511;
            const int c  = r >> 4, e = r & 15;
            float s = 0.f, cc = 0.f;
            #pragma unroll
            for (int k = 0; k < NCOPY; ++k) {
                s  += gload(&gS[k * (N_ * E_ * C_) + (n2 * E_ + e) * C_ + c]);
                cc += gload(&gC[k * (N_ * C_) + n2 * C_ + c]);
            }
            mu[(n2 * C_ + c) * MUP + e] = s / cc;
            if (e == 0) mu[(n2 * C_ + c) * MUP + 16] = 1.0f / (cc * (float)C_);
        }
    }
}

// ---------------------------------------------------------------------------
// Kernel 2: variance (grid-stride, persistent 1024 blocks, mu from ws) +
// finalize folded into the last block (ticket).
// ---------------------------------------------------------------------------
__global__ __launch_bounds__(BLK, 4) void k_var(
    const float4* __restrict__ x4, const int4* __restrict__ t4,
    float* __restrict__ ws, float* __restrict__ out)
{
    __shared__ float s_mu[N_ * C_ * MUP];   // 1280 floats
    __shared__ float s_aux[8];
    __shared__ unsigned s_flag;

    float* gvar = ws + WS_VAR;
    const int bid = blockIdx.x, tid = threadIdx.x;
    const int lane = tid & 63, wid = tid >> 6;

    // prologue: copy the precomputed mu table (means + weights) into LDS
    {
        const float* mu = ws + WS_MU;
        for (int i = tid; i < N_ * C_ * MUP; i += BLK) s_mu[i] = mu[i];
    }
    __syncthreads();

    float va0 = 0.f, va1 = 0.f;
    for (int g = bid * BLK + tid; g < N_ * V4_; g += GV * BLK) {
        const int n  = (g >= V4_) ? 1 : 0;
        const int vg = g - n * V4_;
        const int4 t = t4[g];
        const float4* __restrict__ xr = x4 + (size_t)n * E_ * V4_ + vg;
        float4 xs[16];
        #pragma unroll
        for (int e = 0; e < 16; ++e) xs[e] = xr[(size_t)e * V4_];

        const int mb = n * (C_ * MUP);
        const int b0 = mb + t.x * MUP, b1 = mb + t.y * MUP;
        const int b2 = mb + t.z * MUP, b3 = mb + t.w * MUP;
        const float w0 = s_mu[b0 + 16], w1 = s_mu[b1 + 16];
        const float w2 = s_mu[b2 + 16], w3 = s_mu[b3 + 16];

        float d0 = 0.f, d1 = 0.f, d2 = 0.f, d3 = 0.f;
        #pragma unroll
        for (int e = 0; e < 16; ++e) {
            const float mu0 = s_mu[b0 + e];
            const float mu1 = s_mu[b1 + e];
            const float mu2 = s_mu[b2 + e];
            const float mu3 = s_mu[b3 + e];
            d0 += (xs[e].x - mu0) * (xs[e].x - mu0);
            d1 += (xs[e].y - mu1) * (xs[e].y - mu1);
            d2 += (xs[e].z - mu2) * (xs[e].z - mu2);
            d3 += (xs[e].w - mu3) * (xs[e].w - mu3);
        }
        const float h0 = fmaxf(sqrtf(d0) - DELTA_VAR, 0.f);
        const float h1 = fmaxf(sqrtf(d1) - DELTA_VAR, 0.f);
        const float h2 = fmaxf(sqrtf(d2) - DELTA_VAR, 0.f);
        const float h3 = fmaxf(sqrtf(d3) - DELTA_VAR, 0.f);
        const float vv = h0 * h0 * w0 + h1 * h1 * w1 + h2 * h2 * w2 + h3 * h3 * w3;
        va0 += (n == 0) ? vv : 0.f;
        va1 += (n == 0) ? 0.f : vv;
    }

    #pragma unroll
    for (int off = 32; off > 0; off >>= 1) {
        va0 += __shfl_down(va0, off, 64);
        va1 += __shfl_down(va1, off, 64);
    }
    if (lane == 0) { s_aux[wid * 2] = va0; s_aux[wid * 2 + 1] = va1; }
    __syncthreads();
    if (tid == 0) {
        const float t0 = s_aux[0] + s_aux[2] + s_aux[4] + s_aux[6];
        const float t1 = s_aux[1] + s_aux[3] + s_aux[5] + s_aux[7];
        const int kc = bid & (NCOPY - 1);
        unsafeAtomicAdd(&gvar[kc * N_ + 0], t0);
        unsafeAtomicAdd(&gvar[kc * N_ + 1], t1);
        __threadfence();             // my atomics visible before ticket
        unsigned* tk = (unsigned*)(ws + WS_TK2);
        s_flag = (atomicAdd(tk, 1u) == (unsigned)(GV - 1)) ? 1u : 0u;
    }
    __syncthreads();

    // ---- finalize in the last block: repulsion + regularizer + assemble
    if (s_flag) {
        __threadfence();             // acquire
        float local = 0.f;
        if (tid < NCOPY * N_) local += gload(&gvar[tid]);   // all 16 entries

        for (int n = 0; n < N_; ++n) {
            const float* mu = s_mu + n * (C_ * MUP);
            if (tid < C_) {
                const int c = tid;
                float d2 = 0.f;
                #pragma unroll
                for (int e = 0; e < E_; ++e) {
                    const float m = mu[c * MUP + e];
                    d2 += m * m;
                }
                const float nm = d2 > 0.f ? sqrtf(d2) : 0.f;
                local += GAMMA * nm / (float)C_;
            }
            for (int t2 = tid; t2 < C_ * C_; t2 += BLK) {
                const int i = t2 >> 5, j = t2 & 31;
                if (i != j) {
                    float d2 = 0.f;
                    #pragma unroll
                    for (int e = 0; e < E_; ++e) {
                        const float diff = mu[i * MUP + e] - mu[j * MUP + e];
                        d2 += diff * diff;
                    }
                    const float d = d2 > 0.f ? sqrtf(d2) : 0.f;
                    const float h = fmaxf(2.0f * DELTA_DIST - d, 0.f);
                    local += (h * h) / (float)(C_ * (C_ - 1));
                }
            }
        }

        #pragma unroll
        for (int off = 32; off > 0; off >>= 1)
            local += __shfl_down(local, off, 64);
        if (lane == 0) s_aux[wid] = local;
        __syncthreads();
        if (tid == 0)
            out[0] = (s_aux[0] + s_aux[1] + s_aux[2] + s_aux[3]) / (float)N_;
    }
}

// ---------------------------------------------------------------------------
extern "C" void kernel_launch(void* const* d_in, const int* in_sizes, int n_in,
                              void* d_out, int out_size, void* d_ws, size_t ws_size,
                              hipStream_t stream) {
    const float4* x4 = (const float4*)d_in[0];
    const int4*   t4 = (const int4*)d_in[1];
    float* ws  = (float*)d_ws;
    float* out = (float*)d_out;

    hipMemsetAsync(d_ws, 0, WS_FLOATS * sizeof(float), stream);

    k_sums<<<dim3(GS), BLK, 0, stream>>>(x4, t4, ws);
    k_var <<<dim3(GV), BLK, 0, stream>>>(x4, t4, ws, out);
}

// Round 4
// 348.570 us; speedup vs baseline: 1.3096x; 1.2730x over previous
//
#include <hip/hip_runtime.h>
#include <math.h>

// Problem constants (fixed by the reference's setup_inputs)
constexpr int N_  = 2;
constexpr int E_  = 16;
constexpr int C_  = 32;
constexpr int V_  = 48 * 160 * 160;   // 1,228,800 voxels per batch
constexpr int V4_ = V_ / 4;           // 307,200 float4 groups per batch
constexpr int BLK = 256;

constexpr float DELTA_VAR  = 0.5f;
constexpr float DELTA_DIST = 2.0f;
constexpr float GAMMA      = 0.001f;

// 8-way split accumulators (atomic decontention).
// ws floats: [0,8192) gsumT8[k][n][e][c] ; [8192,8704) gcnt8[k][n][c] ;
//            [8704,8720) gvar8[k][n] ; [8720] ticket
constexpr int NCOPY     = 8;
constexpr int WS_SUMT   = 0;
constexpr int WS_CNT    = WS_SUMT + NCOPY * N_ * E_ * C_;   // 8192
constexpr int WS_VAR    = WS_CNT  + NCOPY * N_ * C_;        // 8704
constexpr int WS_TK     = WS_VAR  + NCOPY * N_;             // 8720
constexpr int WS_FLOATS = WS_TK + 4;                        // 8724

constexpr int MUP = 20;
constexpr int GVB = 1200 * N_;        // total variance blocks (ticket target)

using short8 = __attribute__((ext_vector_type(8))) short;
using f32x4  = __attribute__((ext_vector_type(4))) float;

__device__ __forceinline__ unsigned short f2bf(float f) {
    unsigned u = __float_as_uint(f);
    return (unsigned short)((u + 0x7FFFu + ((u >> 16) & 1u)) >> 16);
}
__device__ __forceinline__ unsigned packlab(int4 t) {
    return (unsigned)t.x | ((unsigned)t.y << 8) | ((unsigned)t.z << 16) | ((unsigned)t.w << 24);
}
// agent-scope (device-coherent) load: reads values written by other blocks'
// device-scope atomics in the SAME kernel, bypassing possibly-stale L1/L2.
__device__ __forceinline__ float gload(const float* p) {
    return __hip_atomic_load(p, __ATOMIC_RELAXED, __HIP_MEMORY_SCOPE_AGENT);
}

// ---------------------------------------------------------------------------
// MFMA segmented sums + counts (R1-proven structure, UNROLLED 4-tile loop).
// Register prefetch, double-buffered LDS, ONE lgkm-only barrier per tile.
// Delta vs R1: label loads issued BEFORE the next-tile prefetch, so the MFMA
// phase's vmcnt wait on labels leaves the prefetch loads in flight.
// grid = (600, N), block = 256 (4 waves). Block owns 2048 contiguous voxels.
// ---------------------------------------------------------------------------
constexpr int XPAD = 520;   // bf16 row stride for the 512-voxel tile
__global__ __launch_bounds__(BLK) void sums_mfma(
    const float4* __restrict__ x4, const int4* __restrict__ t4,
    float* __restrict__ ws)
{
    __shared__ unsigned short s_xb[2][E_ * XPAD];

    const int n     = blockIdx.y;
    const int gtile = blockIdx.x * 2048;
    const int tid   = threadIdx.x;
    const int lane  = tid & 63;
    const int wid   = tid >> 6;
    const int myc   = lane & 15;
    const int quad  = lane >> 4;

    const short one = (short)0x3F80;
    short8 A_ones = {one, one, one, one, one, one, one, one};

    f32x4 acc_lo = {0.f,0.f,0.f,0.f}, acc_hi = {0.f,0.f,0.f,0.f};
    f32x4 cnt_lo = {0.f,0.f,0.f,0.f}, cnt_hi = {0.f,0.f,0.f,0.f};

    // prologue: tile 0 loads
    float4 R[8];
    {
        const int tb4 = gtile >> 2;
        #pragma unroll
        for (int k = 0; k < 8; ++k) {
            const int i = k * BLK + tid, e = i >> 7, v4 = i & 127;
            R[k] = x4[((size_t)(n * E_ + e)) * V4_ + tb4 + v4];
        }
    }

    #pragma unroll
    for (int t = 0; t < 4; ++t) {
        const int tbase4 = (gtile + t * 512) >> 2;
        unsigned short* buf = s_xb[t & 1];

        // convert + LDS stage (bf16)
        #pragma unroll
        for (int k = 0; k < 8; ++k) {
            const int i = k * BLK + tid, e = i >> 7, v4 = i & 127;
            uint2 p;
            p.x = (unsigned)f2bf(R[k].x) | ((unsigned)f2bf(R[k].y) << 16);
            p.y = (unsigned)f2bf(R[k].z) | ((unsigned)f2bf(R[k].w) << 16);
            *(uint2*)&buf[e * XPAD + v4 * 4] = p;
        }
        // labels for this tile FIRST (older vmem ops than the prefetch):
        // the MFMA phase's wait on them won't drain the prefetch.
        const int wbase = wid * 128;
        int4 P[4], Q[4];
        #pragma unroll
        for (int s = 0; s < 4; ++s) {
            const int b4 = tbase4 + ((wbase + s * 32 + quad * 8) >> 2);
            P[s] = t4[(size_t)n * V4_ + b4];
            Q[s] = t4[(size_t)n * V4_ + b4 + 1];
        }
        // prefetch next tile — stays in flight across the raw barrier
        if (t < 3) {
            const int nb4 = (gtile + (t + 1) * 512) >> 2;
            #pragma unroll
            for (int k = 0; k < 8; ++k) {
                const int i = k * BLK + tid, e = i >> 7, v4 = i & 127;
                R[k] = x4[((size_t)(n * E_ + e)) * V4_ + nb4 + v4];
            }
        }

        // lgkm-only barrier: orders ds_writes without draining vmcnt
        __builtin_amdgcn_sched_barrier(0);
        asm volatile("s_waitcnt lgkmcnt(0)");
        __builtin_amdgcn_s_barrier();
        __builtin_amdgcn_sched_barrier(0);

        // MFMA phase: 4 K-steps of 32 voxels over this wave's 128-voxel strip
        #pragma unroll
        for (int s = 0; s < 4; ++s) {
            const int lvb = wbase + s * 32;
            const short8 A = *(const short8*)&buf[myc * XPAD + lvb + quad * 8];
            const unsigned la = packlab(P[s]), lb2 = packlab(Q[s]);
            short8 Blo, Bhi;
            #pragma unroll
            for (int j = 0; j < 4; ++j) {
                const int c0 = (la  >> (8 * j)) & 255;
                const int c1 = (lb2 >> (8 * j)) & 255;
                Blo[j]     = (c0 == myc)      ? one : (short)0;
                Bhi[j]     = (c0 == myc + 16) ? one : (short)0;
                Blo[4 + j] = (c1 == myc)      ? one : (short)0;
                Bhi[4 + j] = (c1 == myc + 16) ? one : (short)0;
            }
            acc_lo = __builtin_amdgcn_mfma_f32_16x16x32_bf16(A,      Blo, acc_lo, 0, 0, 0);
            acc_hi = __builtin_amdgcn_mfma_f32_16x16x32_bf16(A,      Bhi, acc_hi, 0, 0, 0);
            cnt_lo = __builtin_amdgcn_mfma_f32_16x16x32_bf16(A_ones, Blo, cnt_lo, 0, 0, 0);
            cnt_hi = __builtin_amdgcn_mfma_f32_16x16x32_bf16(A_ones, Bhi, cnt_hi, 0, 0, 0);
        }
    }

    // ---- epilogue: cross-wave LDS reduce, then 512 (+32) atomics per BLOCK
    // into one of 8 split copies (blockIdx.x & 7). Buffer-0 overlay is safe:
    // last MFMA tile read buffer 1, and all waves passed that barrier.
    float* s_red = (float*)&s_xb[0][0];   // 2048 sums + 128 counts
    #pragma unroll
    for (int r = 0; r < 4; ++r) {
        s_red[wid * 512 + lane * 8 + r]     = acc_lo[r];
        s_red[wid * 512 + lane * 8 + 4 + r] = acc_hi[r];
    }
    if (quad == 0) {
        s_red[2048 + wid * 32 + myc]      = cnt_lo[0];
        s_red[2048 + wid * 32 + myc + 16] = cnt_hi[0];
    }
    __syncthreads();

    const int kc = blockIdx.x & (NCOPY - 1);
    float* gsumT = ws + WS_SUMT + kc * (N_ * E_ * C_);
    float* gcntk = ws + WS_CNT  + kc * (N_ * C_);
    #pragma unroll
    for (int u = 0; u < 2; ++u) {
        const int combo = tid * 2 + u;              // 0..511
        const int l = combo >> 3, k = combo & 7;
        const int e = (l >> 4) * 4 + (k & 3);
        const int c = (l & 15) + 16 * (k >> 2);
        const float v = s_red[combo] + s_red[512 + combo]
                      + s_red[1024 + combo] + s_red[1536 + combo];
        unsafeAtomicAdd(&gsumT[(n * E_ + e) * C_ + c], v);
    }
    if (tid < C_) {
        const float v = s_red[2048 + tid] + s_red[2048 + 32 + tid]
                      + s_red[2048 + 64 + tid] + s_red[2048 + 96 + tid];
        unsafeAtomicAdd(&gcntk[n * C_ + tid], v);
    }
}

// ---------------------------------------------------------------------------
// Variance (R1-proven body) + finalize folded into the LAST block (ticket —
// the pattern R3's k_var validated as fast). grid = (1200, N), block = 256.
// ---------------------------------------------------------------------------
__global__ __launch_bounds__(BLK) void variance_f32(
    const float4* __restrict__ x4, const int4* __restrict__ t4,
    float* __restrict__ ws, float* __restrict__ out)
{
    __shared__ float s_mu[C_ * MUP];
    __shared__ float s_part[4];
    __shared__ float s_mean[C_ * 17];
    __shared__ float s_red2, s_total;
    __shared__ unsigned s_flag;

    const float* gsumT = ws + WS_SUMT;
    const float* gcnt  = ws + WS_CNT;
    float*       gvar  = ws + WS_VAR;

    const int n = blockIdx.y, tid = threadIdx.x;
    const int v4g = blockIdx.x * BLK + tid;

    // issue the big loads first so they fly during the mu build
    const int4 t = t4[(size_t)n * V4_ + v4g];
    const float4* __restrict__ xrow = x4 + (size_t)n * E_ * V4_ + v4g;
    float4 xs[16];
    #pragma unroll
    for (int e = 0; e < 16; ++e) xs[e] = xrow[(size_t)e * V4_];

    for (int i = tid; i < C_ * E_; i += BLK) {
        const int c = i >> 4, e = i & 15;
        float s = 0.f, cc = 0.f;
        #pragma unroll
        for (int k = 0; k < NCOPY; ++k) {
            s  += gsumT[k * (N_ * E_ * C_) + (n * E_ + e) * C_ + c];
            cc += gcnt [k * (N_ * C_) + n * C_ + c];
        }
        s_mu[c * MUP + e] = s / cc;
        if (e == 0) s_mu[c * MUP + 16] = 1.0f / (cc * (float)C_);
    }
    __syncthreads();

    const int l0 = t.x, l1 = t.y, l2 = t.z, l3 = t.w;
    float4 m0[4], m1[4], m2[4], m3[4];
    #pragma unroll
    for (int u = 0; u < 4; ++u) {
        m0[u] = *(const float4*)&s_mu[l0 * MUP + 4 * u];
        m1[u] = *(const float4*)&s_mu[l1 * MUP + 4 * u];
        m2[u] = *(const float4*)&s_mu[l2 * MUP + 4 * u];
        m3[u] = *(const float4*)&s_mu[l3 * MUP + 4 * u];
    }
    const float w0 = s_mu[l0 * MUP + 16], w1 = s_mu[l1 * MUP + 16];
    const float w2 = s_mu[l2 * MUP + 16], w3 = s_mu[l3 * MUP + 16];

    float d0 = 0.f, d1 = 0.f, d2 = 0.f, d3 = 0.f;
    #pragma unroll
    for (int e = 0; e < 16; ++e) {
        const float mu0 = ((const float*)&m0[e >> 2])[e & 3];
        const float mu1 = ((const float*)&m1[e >> 2])[e & 3];
        const float mu2 = ((const float*)&m2[e >> 2])[e & 3];
        const float mu3 = ((const float*)&m3[e >> 2])[e & 3];
        d0 += (xs[e].x - mu0) * (xs[e].x - mu0);
        d1 += (xs[e].y - mu1) * (xs[e].y - mu1);
        d2 += (xs[e].z - mu2) * (xs[e].z - mu2);
        d3 += (xs[e].w - mu3) * (xs[e].w - mu3);
    }
    const float h0 = fmaxf(sqrtf(d0) - DELTA_VAR, 0.f);
    const float h1 = fmaxf(sqrtf(d1) - DELTA_VAR, 0.f);
    const float h2 = fmaxf(sqrtf(d2) - DELTA_VAR, 0.f);
    const float h3 = fmaxf(sqrtf(d3) - DELTA_VAR, 0.f);
    float v = h0 * h0 * w0 + h1 * h1 * w1 + h2 * h2 * w2 + h3 * h3 * w3;

    #pragma unroll
    for (int off = 32; off > 0; off >>= 1)
        v += __shfl_down(v, off, 64);
    if ((tid & 63) == 0) s_part[tid >> 6] = v;
    __syncthreads();
    if (tid == 0) {
        const int kc = (blockIdx.y * gridDim.x + blockIdx.x) & (NCOPY - 1);
        unsafeAtomicAdd(&gvar[kc * N_ + n],
                        s_part[0] + s_part[1] + s_part[2] + s_part[3]);
        __threadfence();             // my atomic visible before the ticket
        unsigned* tk = (unsigned*)(ws + WS_TK);
        s_flag = (atomicAdd(tk, 1u) == (unsigned)(GVB - 1)) ? 1u : 0u;
    }
    __syncthreads();

    // ---- finalize in the last block: repulsion + regularizer + assemble
    if (s_flag) {
        __threadfence();             // acquire: other blocks' gvar atomics
        if (tid == 0) s_total = 0.0f;

        for (int nn = 0; nn < N_; ++nn) {
            __syncthreads();
            for (int i = tid; i < C_ * E_; i += BLK) {
                const int c = i >> 4, e = i & 15;
                float s = 0.f, cc = 0.f;
                #pragma unroll
                for (int k = 0; k < NCOPY; ++k) {
                    s  += gsumT[k * (N_ * E_ * C_) + (nn * E_ + e) * C_ + c];
                    cc += gcnt [k * (N_ * C_) + nn * C_ + c];
                }
                s_mean[c * 17 + e] = s / cc;
            }
            if (tid == 0) {
                float vs = 0.f;
                #pragma unroll
                for (int k = 0; k < NCOPY; ++k) vs += gload(&gvar[k * N_ + nn]);
                s_red2 = vs;
            }
            __syncthreads();

            float local = 0.0f;
            if (tid < C_) {
                const int c = tid;
                float dd = 0.f;
                #pragma unroll
                for (int e = 0; e < E_; ++e) {
                    const float m = s_mean[c * 17 + e];
                    dd += m * m;
                }
                const float nm = dd > 0.f ? sqrtf(dd) : 0.f;
                local += GAMMA * nm / (float)C_;
            }
            for (int t2 = tid; t2 < C_ * C_; t2 += BLK) {
                const int i = t2 >> 5, j = t2 & 31;
                if (i != j) {
                    float dd = 0.f;
                    #pragma unroll
                    for (int e = 0; e < E_; ++e) {
                        const float diff = s_mean[i * 17 + e] - s_mean[j * 17 + e];
                        dd += diff * diff;
                    }
                    const float d = dd > 0.f ? sqrtf(dd) : 0.f;
                    const float h = fmaxf(2.0f * DELTA_DIST - d, 0.f);
                    local += (h * h) / (float)(C_ * (C_ - 1));
                }
            }
            unsafeAtomicAdd(&s_red2, local);
            __syncthreads();
            if (tid == 0) s_total += s_red2;
        }
        __syncthreads();
        if (tid == 0) out[0] = s_total / (float)N_;
    }
}

// ---------------------------------------------------------------------------
extern "C" void kernel_launch(void* const* d_in, const int* in_sizes, int n_in,
                              void* d_out, int out_size, void* d_ws, size_t ws_size,
                              hipStream_t stream) {
    const float4* x4 = (const float4*)d_in[0];
    const int4*   t4 = (const int4*)d_in[1];
    float* ws  = (float*)d_ws;
    float* out = (float*)d_out;

    hipMemsetAsync(d_ws, 0, WS_FLOATS * sizeof(float), stream);

    sums_mfma   <<<dim3(600, N_),  BLK, 0, stream>>>(x4, t4, ws);
    variance_f32<<<dim3(1200, N_), BLK, 0, stream>>>(x4, t4, ws, out);
}

// Round 5
// 298.568 us; speedup vs baseline: 1.5290x; 1.1675x over previous
//
#include <hip/hip_runtime.h>
#include <math.h>

// Problem constants (fixed by the reference's setup_inputs)
constexpr int N_  = 2;
constexpr int E_  = 16;
constexpr int C_  = 32;
constexpr int V_  = 48 * 160 * 160;   // 1,228,800 voxels per batch
constexpr int V4_ = V_ / 4;           // 307,200 float4 groups per batch
constexpr int BLK = 256;

constexpr float DELTA_VAR  = 0.5f;
constexpr float DELTA_DIST = 2.0f;
constexpr float GAMMA      = 0.001f;

// 8-way split accumulators (atomic decontention).
// ws floats: [0,8192) gsumT8[k][n][e][c] ; [8192,8704) gcnt8[k][n][c] ;
//            [8704,8720) gvar8[k][n] ; [8720] ticket ; [8724,10004) mu
constexpr int NCOPY     = 8;
constexpr int MUP       = 20;
constexpr int WS_SUMT   = 0;
constexpr int WS_CNT    = WS_SUMT + NCOPY * N_ * E_ * C_;   // 8192
constexpr int WS_VAR    = WS_CNT  + NCOPY * N_ * C_;        // 8704
constexpr int WS_TK     = WS_VAR  + NCOPY * N_;             // 8720
constexpr int WS_MU     = WS_TK + 4;                        // 8724
constexpr int WS_ZERO   = WS_TK + 4;                        // memset range (mu fully overwritten)

constexpr int GV = 1024;              // variance grid: persistent, 4 blocks/CU

using short8 = __attribute__((ext_vector_type(8))) short;
using f32x4  = __attribute__((ext_vector_type(4))) float;

__device__ __forceinline__ unsigned short f2bf(float f) {
    unsigned u = __float_as_uint(f);
    return (unsigned short)((u + 0x7FFFu + ((u >> 16) & 1u)) >> 16);
}
__device__ __forceinline__ unsigned packlab(int4 t) {
    return (unsigned)t.x | ((unsigned)t.y << 8) | ((unsigned)t.z << 16) | ((unsigned)t.w << 24);
}
// agent-scope (device-coherent) load: reads values written by other blocks'
// device-scope atomics in the SAME kernel, bypassing possibly-stale L1/L2.
__device__ __forceinline__ float gload(const float* p) {
    return __hip_atomic_load(p, __ATOMIC_RELAXED, __HIP_MEMORY_SCOPE_AGENT);
}

// ---------------------------------------------------------------------------
// Kernel 1: MFMA segmented sums + counts — BYTE-IDENTICAL to R4's proven-fast
// version. grid = (600, N), block = 256 (4 waves), 2048 voxels per block.
// ---------------------------------------------------------------------------
constexpr int XPAD = 520;   // bf16 row stride for the 512-voxel tile
__global__ __launch_bounds__(BLK) void sums_mfma(
    const float4* __restrict__ x4, const int4* __restrict__ t4,
    float* __restrict__ ws)
{
    __shared__ unsigned short s_xb[2][E_ * XPAD];

    const int n     = blockIdx.y;
    const int gtile = blockIdx.x * 2048;
    const int tid   = threadIdx.x;
    const int lane  = tid & 63;
    const int wid   = tid >> 6;
    const int myc   = lane & 15;
    const int quad  = lane >> 4;

    const short one = (short)0x3F80;
    short8 A_ones = {one, one, one, one, one, one, one, one};

    f32x4 acc_lo = {0.f,0.f,0.f,0.f}, acc_hi = {0.f,0.f,0.f,0.f};
    f32x4 cnt_lo = {0.f,0.f,0.f,0.f}, cnt_hi = {0.f,0.f,0.f,0.f};

    // prologue: tile 0 loads
    float4 R[8];
    {
        const int tb4 = gtile >> 2;
        #pragma unroll
        for (int k = 0; k < 8; ++k) {
            const int i = k * BLK + tid, e = i >> 7, v4 = i & 127;
            R[k] = x4[((size_t)(n * E_ + e)) * V4_ + tb4 + v4];
        }
    }

    #pragma unroll
    for (int t = 0; t < 4; ++t) {
        const int tbase4 = (gtile + t * 512) >> 2;
        unsigned short* buf = s_xb[t & 1];

        // convert + LDS stage (bf16)
        #pragma unroll
        for (int k = 0; k < 8; ++k) {
            const int i = k * BLK + tid, e = i >> 7, v4 = i & 127;
            uint2 p;
            p.x = (unsigned)f2bf(R[k].x) | ((unsigned)f2bf(R[k].y) << 16);
            p.y = (unsigned)f2bf(R[k].z) | ((unsigned)f2bf(R[k].w) << 16);
            *(uint2*)&buf[e * XPAD + v4 * 4] = p;
        }
        // labels for this tile FIRST (older vmem ops than the prefetch)
        const int wbase = wid * 128;
        int4 P[4], Q[4];
        #pragma unroll
        for (int s = 0; s < 4; ++s) {
            const int b4 = tbase4 + ((wbase + s * 32 + quad * 8) >> 2);
            P[s] = t4[(size_t)n * V4_ + b4];
            Q[s] = t4[(size_t)n * V4_ + b4 + 1];
        }
        // prefetch next tile — stays in flight across the raw barrier
        if (t < 3) {
            const int nb4 = (gtile + (t + 1) * 512) >> 2;
            #pragma unroll
            for (int k = 0; k < 8; ++k) {
                const int i = k * BLK + tid, e = i >> 7, v4 = i & 127;
                R[k] = x4[((size_t)(n * E_ + e)) * V4_ + nb4 + v4];
            }
        }

        // lgkm-only barrier: orders ds_writes without draining vmcnt
        __builtin_amdgcn_sched_barrier(0);
        asm volatile("s_waitcnt lgkmcnt(0)");
        __builtin_amdgcn_s_barrier();
        __builtin_amdgcn_sched_barrier(0);

        // MFMA phase: 4 K-steps of 32 voxels over this wave's 128-voxel strip
        #pragma unroll
        for (int s = 0; s < 4; ++s) {
            const int lvb = wbase + s * 32;
            const short8 A = *(const short8*)&buf[myc * XPAD + lvb + quad * 8];
            const unsigned la = packlab(P[s]), lb2 = packlab(Q[s]);
            short8 Blo, Bhi;
            #pragma unroll
            for (int j = 0; j < 4; ++j) {
                const int c0 = (la  >> (8 * j)) & 255;
                const int c1 = (lb2 >> (8 * j)) & 255;
                Blo[j]     = (c0 == myc)      ? one : (short)0;
                Bhi[j]     = (c0 == myc + 16) ? one : (short)0;
                Blo[4 + j] = (c1 == myc)      ? one : (short)0;
                Bhi[4 + j] = (c1 == myc + 16) ? one : (short)0;
            }
            acc_lo = __builtin_amdgcn_mfma_f32_16x16x32_bf16(A,      Blo, acc_lo, 0, 0, 0);
            acc_hi = __builtin_amdgcn_mfma_f32_16x16x32_bf16(A,      Bhi, acc_hi, 0, 0, 0);
            cnt_lo = __builtin_amdgcn_mfma_f32_16x16x32_bf16(A_ones, Blo, cnt_lo, 0, 0, 0);
            cnt_hi = __builtin_amdgcn_mfma_f32_16x16x32_bf16(A_ones, Bhi, cnt_hi, 0, 0, 0);
        }
    }

    // ---- epilogue: cross-wave LDS reduce, then 512 (+32) atomics per BLOCK
    float* s_red = (float*)&s_xb[0][0];   // 2048 sums + 128 counts
    #pragma unroll
    for (int r = 0; r < 4; ++r) {
        s_red[wid * 512 + lane * 8 + r]     = acc_lo[r];
        s_red[wid * 512 + lane * 8 + 4 + r] = acc_hi[r];
    }
    if (quad == 0) {
        s_red[2048 + wid * 32 + myc]      = cnt_lo[0];
        s_red[2048 + wid * 32 + myc + 16] = cnt_hi[0];
    }
    __syncthreads();

    const int kc = blockIdx.x & (NCOPY - 1);
    float* gsumT = ws + WS_SUMT + kc * (N_ * E_ * C_);
    float* gcntk = ws + WS_CNT  + kc * (N_ * C_);
    #pragma unroll
    for (int u = 0; u < 2; ++u) {
        const int combo = tid * 2 + u;              // 0..511
        const int l = combo >> 3, k = combo & 7;
        const int e = (l >> 4) * 4 + (k & 3);
        const int c = (l & 15) + 16 * (k >> 2);
        const float v = s_red[combo] + s_red[512 + combo]
                      + s_red[1024 + combo] + s_red[1536 + combo];
        unsafeAtomicAdd(&gsumT[(n * E_ + e) * C_ + c], v);
    }
    if (tid < C_) {
        const float v = s_red[2048 + tid] + s_red[2048 + 32 + tid]
                      + s_red[2048 + 64 + tid] + s_red[2048 + 96 + tid];
        unsafeAtomicAdd(&gcntk[n * C_ + tid], v);
    }
}

// ---------------------------------------------------------------------------
// Kernel 2: tiny single-block mu build (means + hinge weights into ws).
// Inter-kernel ordering makes the sums atomics coherent here — plain loads.
// ---------------------------------------------------------------------------
__global__ __launch_bounds__(BLK) void k_mu(float* __restrict__ ws)
{
    const float* gS = ws + WS_SUMT;
    const float* gC = ws + WS_CNT;
    float*       mu = ws + WS_MU;
    const int tid = threadIdx.x;
    for (int i = tid; i < N_ * C_ * E_; i += BLK) {
        const int n2 = i >> 9;            // C_*E_ = 512
        const int r  = i & 511;
        const int c  = r >> 4, e = r & 15;
        float s = 0.f, cc = 0.f;
        #pragma unroll
        for (int k = 0; k < NCOPY; ++k) {
            s  += gS[k * (N_ * E_ * C_) + (n2 * E_ + e) * C_ + c];
            cc += gC[k * (N_ * C_) + n2 * C_ + c];
        }
        mu[(n2 * C_ + c) * MUP + e] = s / cc;
        if (e == 0) mu[(n2 * C_ + c) * MUP + 16] = 1.0f / (cc * (float)C_);
    }
}

// ---------------------------------------------------------------------------
// Kernel 3: variance — R3's measured-fast body. Persistent 1024 blocks,
// grid-stride, mu copied from ws into LDS once, finalize fused into the
// LAST block (ticket). 4 blocks/CU.
// ---------------------------------------------------------------------------
__global__ __launch_bounds__(BLK, 4) void k_var(
    const float4* __restrict__ x4, const int4* __restrict__ t4,
    float* __restrict__ ws, float* __restrict__ out)
{
    __shared__ float s_mu[N_ * C_ * MUP];   // 1280 floats: both batches
    __shared__ float s_aux[8];
    __shared__ unsigned s_flag;

    float* gvar = ws + WS_VAR;
    const int bid = blockIdx.x, tid = threadIdx.x;
    const int lane = tid & 63, wid = tid >> 6;

    // prologue: copy the precomputed mu table (means + weights) into LDS
    {
        const float* mu = ws + WS_MU;
        for (int i = tid; i < N_ * C_ * MUP; i += BLK) s_mu[i] = mu[i];
    }
    __syncthreads();

    float va0 = 0.f, va1 = 0.f;
    for (int g = bid * BLK + tid; g < N_ * V4_; g += GV * BLK) {
        const int n  = (g >= V4_) ? 1 : 0;
        const int vg = g - n * V4_;
        const int4 t = t4[g];
        const float4* __restrict__ xr = x4 + (size_t)n * E_ * V4_ + vg;
        float4 xs[16];
        #pragma unroll
        for (int e = 0; e < 16; ++e) xs[e] = xr[(size_t)e * V4_];

        const int mb = n * (C_ * MUP);
        const int b0 = mb + t.x * MUP, b1 = mb + t.y * MUP;
        const int b2 = mb + t.z * MUP, b3 = mb + t.w * MUP;
        const float w0 = s_mu[b0 + 16], w1 = s_mu[b1 + 16];
        const float w2 = s_mu[b2 + 16], w3 = s_mu[b3 + 16];

        float d0 = 0.f, d1 = 0.f, d2 = 0.f, d3 = 0.f;
        #pragma unroll
        for (int e = 0; e < 16; ++e) {
            const float mu0 = s_mu[b0 + e];
            const float mu1 = s_mu[b1 + e];
            const float mu2 = s_mu[b2 + e];
            const float mu3 = s_mu[b3 + e];
            d0 += (xs[e].x - mu0) * (xs[e].x - mu0);
            d1 += (xs[e].y - mu1) * (xs[e].y - mu1);
            d2 += (xs[e].z - mu2) * (xs[e].z - mu2);
            d3 += (xs[e].w - mu3) * (xs[e].w - mu3);
        }
        const float h0 = fmaxf(sqrtf(d0) - DELTA_VAR, 0.f);
        const float h1 = fmaxf(sqrtf(d1) - DELTA_VAR, 0.f);
        const float h2 = fmaxf(sqrtf(d2) - DELTA_VAR, 0.f);
        const float h3 = fmaxf(sqrtf(d3) - DELTA_VAR, 0.f);
        const float vv = h0 * h0 * w0 + h1 * h1 * w1 + h2 * h2 * w2 + h3 * h3 * w3;
        va0 += (n == 0) ? vv : 0.f;
        va1 += (n == 0) ? 0.f : vv;
    }

    #pragma unroll
    for (int off = 32; off > 0; off >>= 1) {
        va0 += __shfl_down(va0, off, 64);
        va1 += __shfl_down(va1, off, 64);
    }
    if (lane == 0) { s_aux[wid * 2] = va0; s_aux[wid * 2 + 1] = va1; }
    __syncthreads();
    if (tid == 0) {
        const float t0 = s_aux[0] + s_aux[2] + s_aux[4] + s_aux[6];
        const float t1 = s_aux[1] + s_aux[3] + s_aux[5] + s_aux[7];
        const int kc = bid & (NCOPY - 1);
        unsafeAtomicAdd(&gvar[kc * N_ + 0], t0);
        unsafeAtomicAdd(&gvar[kc * N_ + 1], t1);
        __threadfence();             // my atomics visible before the ticket
        unsigned* tk = (unsigned*)(ws + WS_TK);
        s_flag = (atomicAdd(tk, 1u) == (unsigned)(GV - 1)) ? 1u : 0u;
    }
    __syncthreads();

    // ---- finalize in the last block: repulsion + regularizer + assemble
    if (s_flag) {
        __threadfence();             // acquire: other blocks' gvar atomics
        float local = 0.f;
        if (tid < NCOPY * N_) local += gload(&gvar[tid]);   // all 16 entries

        for (int n = 0; n < N_; ++n) {
            const float* mu = s_mu + n * (C_ * MUP);
            if (tid < C_) {
                const int c = tid;
                float d2 = 0.f;
                #pragma unroll
                for (int e = 0; e < E_; ++e) {
                    const float m = mu[c * MUP + e];
                    d2 += m * m;
                }
                const float nm = d2 > 0.f ? sqrtf(d2) : 0.f;
                local += GAMMA * nm / (float)C_;
            }
            for (int t2 = tid; t2 < C_ * C_; t2 += BLK) {
                const int i = t2 >> 5, j = t2 & 31;
                if (i != j) {
                    float d2 = 0.f;
                    #pragma unroll
                    for (int e = 0; e < E_; ++e) {
                        const float diff = mu[i * MUP + e] - mu[j * MUP + e];
                        d2 += diff * diff;
                    }
                    const float d = d2 > 0.f ? sqrtf(d2) : 0.f;
                    const float h = fmaxf(2.0f * DELTA_DIST - d, 0.f);
                    local += (h * h) / (float)(C_ * (C_ - 1));
                }
            }
        }

        #pragma unroll
        for (int off = 32; off > 0; off >>= 1)
            local += __shfl_down(local, off, 64);
        if (lane == 0) s_aux[wid] = local;
        __syncthreads();
        if (tid == 0)
            out[0] = (s_aux[0] + s_aux[1] + s_aux[2] + s_aux[3]) / (float)N_;
    }
}

// ---------------------------------------------------------------------------
extern "C" void kernel_launch(void* const* d_in, const int* in_sizes, int n_in,
                              void* d_out, int out_size, void* d_ws, size_t ws_size,
                              hipStream_t stream) {
    const float4* x4 = (const float4*)d_in[0];
    const int4*   t4 = (const int4*)d_in[1];
    float* ws  = (float*)d_ws;
    float* out = (float*)d_out;

    hipMemsetAsync(d_ws, 0, WS_ZERO * sizeof(float), stream);

    sums_mfma<<<dim3(600, N_), BLK, 0, stream>>>(x4, t4, ws);
    k_mu     <<<1,             BLK, 0, stream>>>(ws);
    k_var    <<<dim3(GV),      BLK, 0, stream>>>(x4, t4, ws, out);
}